// Round 8
// baseline (211.651 us; speedup 1.0000x reference)
//
#include <hip/hip_runtime.h>
#include <stdint.h>

#define B2 128
#define NSEQ 256
#define DIM 256
#define NH 8
#define CH 32

typedef __attribute__((ext_vector_type(8))) __bf16 bf16x8;
typedef __attribute__((ext_vector_type(8))) unsigned short u16x8;
typedef __attribute__((ext_vector_type(4))) unsigned short u16x4;
typedef __attribute__((ext_vector_type(4))) unsigned int u32x4;
typedef __attribute__((ext_vector_type(4))) float f32x4;

__device__ __forceinline__ unsigned short f2bf(float f) {
  unsigned int u = __builtin_bit_cast(unsigned int, f);
  u += 0x7FFFu + ((u >> 16) & 1u);
  return (unsigned short)(u >> 16);
}
__device__ __forceinline__ float bf2f(unsigned short h) {
  unsigned int u = ((unsigned int)h) << 16;
  return __builtin_bit_cast(float, u);
}
__device__ __forceinline__ bf16x8 as_bf(u16x8 v) { return __builtin_bit_cast(bf16x8, v); }
__device__ __forceinline__ unsigned int cvtpk(float lo, float hi) {
  unsigned int r;
  asm("v_cvt_pk_bf16_f32 %0, %1, %2" : "=v"(r) : "v"(lo), "v"(hi));
  return r;
}

__device__ __forceinline__ void gload16(void* lds, const void* g) {
  __builtin_amdgcn_global_load_lds(
      (__attribute__((address_space(1))) void*)(g),
      (__attribute__((address_space(3))) void*)(lds), 16, 0, 0);
}

// ---------------- K0: fp32 -> bf16 conversion ----------------
__global__ void k_convert(const float* __restrict__ x, const float* __restrict__ wqkv,
                          const float* __restrict__ wgate, const float* __restrict__ wo,
                          unsigned short* __restrict__ xb, unsigned short* __restrict__ wallb,
                          unsigned short* __restrict__ wob) {
  const int NX = 8388608, NWALL = 262144, NWO = 65536;
  int i = blockIdx.x * blockDim.x + threadIdx.x;
  int total4 = (NX + NWALL + NWO) >> 2;
  if (i >= total4) return;
  int e = i << 2;
  float4 v;
  unsigned short* dst;
  if (e < NX) {
    v = *reinterpret_cast<const float4*>(x + e);
    dst = xb + e;
  } else if (e < NX + NWALL) {
    int o = e - NX;
    v = (o < 196608) ? *reinterpret_cast<const float4*>(wqkv + o)
                     : *reinterpret_cast<const float4*>(wgate + (o - 196608));
    dst = wallb + o;
  } else {
    int o = e - NX - NWALL;
    v = *reinterpret_cast<const float4*>(wo + o);
    dst = wob + o;
  }
  u16x4 r;
  r[0] = f2bf(v.x); r[1] = f2bf(v.y); r[2] = f2bf(v.z); r[3] = f2bf(v.w);
  *reinterpret_cast<u16x4*>(dst) = r;
}

// ---------------- K1/K3: GEMM  Y = A(bf16) * Bw(bf16)^T ----------------
// 1D grid; XCD-grouping swizzle: blocks sharing an A-tile (same m0) keep bid%8
// identical -> same XCD -> A-tile L2 reuse. MODE 0: 2048 blocks (n in 8 tiles).
// MODE 1: 512 blocks (n in 2 tiles).
template <int MODE>
__launch_bounds__(256, 2)
__global__ void k_gemm(const unsigned short* __restrict__ A, const unsigned short* __restrict__ Bw,
                       unsigned short* __restrict__ qs, unsigned short* __restrict__ ksb,
                       unsigned short* __restrict__ vsb, unsigned short* __restrict__ gateb,
                       const float* __restrict__ gbias,
                       float* __restrict__ outp, const float* __restrict__ bo) {
  __shared__ __attribute__((aligned(16))) unsigned short As[2][8192];  // [128][64] bf16, swizzled
  __shared__ __attribute__((aligned(16))) unsigned short Bs[2][8192];
  const int tid = threadIdx.x, lane = tid & 63, w = tid >> 6;
  const int wr = w >> 1, wc = w & 1;
  const int bid = blockIdx.x;
  int m0, n0;
  if (MODE == 0) { m0 = ((bid & 7) + ((bid >> 6) << 3)) * 128; n0 = ((bid >> 3) & 7) * 128; }
  else           { m0 = ((bid & 7) + ((bid >> 4) << 3)) * 128; n0 = ((bid >> 3) & 1) * 128; }

  auto stage = [&](unsigned short* sbuf, const unsigned short* gsrc, int row0, int k0) {
#pragma unroll
    for (int q2 = 0; q2 < 4; ++q2) {
      int ob = (w * 4 + q2) * 1024 + (lane << 4);
      int r = ob >> 7, cb = ob & 127;
      int scb = cb ^ ((r & 7) << 4);
      const unsigned short* g = gsrc + (size_t)(row0 + r) * 256 + k0 + (scb >> 1);
      gload16(sbuf + (size_t)(w * 4 + q2) * 512, g);
    }
  };

  f32x4 acc[4][4];
#pragma unroll
  for (int i = 0; i < 4; ++i) {
#pragma unroll
    for (int j = 0; j < 4; ++j) acc[i][j] = (f32x4){0.f, 0.f, 0.f, 0.f};
  }

  stage(As[0], A, m0, 0);
  stage(Bs[0], Bw, n0, 0);
  asm volatile("s_waitcnt vmcnt(0)" ::: "memory");
  __syncthreads();

#pragma unroll
  for (int kt = 0; kt < 4; ++kt) {
    const int cur = kt & 1;
    if (kt < 3) {
      stage(As[cur ^ 1], A, m0, (kt + 1) * 64);
      stage(Bs[cur ^ 1], Bw, n0, (kt + 1) * 64);
    }
#pragma unroll
    for (int kk = 0; kk < 2; ++kk) {
      bf16x8 af[4], bfv[4];
      const int cb = kk * 64 + ((lane >> 4) << 4);
#pragma unroll
      for (int fr = 0; fr < 4; ++fr) {
        int ra = wr * 64 + fr * 16 + (lane & 15);
        int off = ra * 128 + (cb ^ ((ra & 7) << 4));
        af[fr] = *reinterpret_cast<const bf16x8*>((const char*)As[cur] + off);
      }
#pragma unroll
      for (int fc = 0; fc < 4; ++fc) {
        int rb = wc * 64 + fc * 16 + (lane & 15);
        int off = rb * 128 + (cb ^ ((rb & 7) << 4));
        bfv[fc] = *reinterpret_cast<const bf16x8*>((const char*)Bs[cur] + off);
      }
#pragma unroll
      for (int fr = 0; fr < 4; ++fr) {
#pragma unroll
        for (int fc = 0; fc < 4; ++fc)
          acc[fr][fc] = __builtin_amdgcn_mfma_f32_16x16x32_bf16(af[fr], bfv[fc], acc[fr][fc], 0, 0, 0);
      }
    }
    asm volatile("s_waitcnt vmcnt(0)" ::: "memory");
    __syncthreads();
  }

  if (MODE == 0) {
#pragma unroll
    for (int fr = 0; fr < 4; ++fr) {
      int mrow = m0 + wr * 64 + fr * 16 + ((lane >> 4) << 2);
      int b = mrow >> 8, n = mrow & 255;
#pragma unroll
      for (int fc = 0; fc < 4; ++fc) {
        int e = n0 + wc * 64 + fc * 16 + (lane & 15);
        int which = e >> 8, loc = e & 255, hh = loc >> 5, cc = loc & 31;
#pragma unroll
        for (int i = 0; i < 4; ++i) {
          float v = acc[fr][fc][i];
          size_t idx = ((size_t)(b * 8 + hh) * 256 + (n + i)) * 32 + cc;
          if (which == 0) {
            qs[idx] = f2bf(v * 0.17677669529663687f);  // C^-0.5
          } else if (which == 1) {
            ksb[idx] = f2bf(v);
          } else if (which == 2) {
            vsb[idx] = f2bf(v);
          } else {
            float gsig = 1.0f / (1.0f + __expf(-(v + gbias[loc])));
            gateb[idx] = f2bf(gsig);  // [bh][n][c] layout, same as q/k/v
          }
        }
      }
    }
  } else {
#pragma unroll
    for (int fr = 0; fr < 4; ++fr) {
      int mrow = m0 + wr * 64 + fr * 16 + ((lane >> 4) << 2);
#pragma unroll
      for (int fc = 0; fc < 4; ++fc) {
        int e = n0 + wc * 64 + fc * 16 + (lane & 15);
        float bb = bo[e];
#pragma unroll
        for (int i = 0; i < 4; ++i)
          outp[(size_t)(mrow + i) * 256 + e] = acc[fr][fc][i] + bb;
      }
    }
  }
}

// ---------------- K2: attention per (b2, head) ----------------
// S^T = mfma(K,Q): lane(l15,hi) holds S[q=l15][key=16kt+4hi+i]. K staged in LDS
// (defeats compiler load-sinking), V^T XOR-swizzled in LDS, P kept IN REGISTERS:
// cvt_pk pairs -> 8 shfl per 32-key PV step assemble the A-fragment. No barriers
// or lgkmcnt stops inside the fr loop.
__launch_bounds__(256, 3)
__global__ void k_attn(const unsigned short* __restrict__ qs, const unsigned short* __restrict__ ksb,
                       const unsigned short* __restrict__ vsb, const unsigned short* __restrict__ gateb,
                       const float* __restrict__ mask, const float* __restrict__ nb,
                       unsigned short* __restrict__ wag) {
  __shared__ __attribute__((aligned(16))) unsigned short Kl[256 * 40];  // [key][c], stride 40
  __shared__ __attribute__((aligned(16))) unsigned short vt[32 * 256];  // [c][key], byte ^ ((c&15)<<4)
  __shared__ __attribute__((aligned(16))) float mb[256];
  const int tid = threadIdx.x, lane = tid & 63, w = tid >> 6;
  const int l15 = lane & 15, hi = lane >> 4;
  const int b = blockIdx.x, h = blockIdx.y;
  const size_t bh = (size_t)(b * 8 + h);
  const unsigned short* kbase = ksb + bh * 8192;
  const unsigned short* vbase = vsb + bh * 8192;
  const unsigned short* qbase = qs + bh * 8192;
  const unsigned short* gbase = gateb + bh * 8192;
  const float* nbh = nb + (size_t)h * 65536;

  mb[tid] = 1e9f * (mask[b * 256 + tid] - 1.0f);
  {
    // V transpose: thread tid owns key=tid; write vt[c][tid] swizzled.
    const unsigned short* vrow = vbase + tid * 32;
#pragma unroll
    for (int c0 = 0; c0 < 32; c0 += 8) {
      u16x8 vv = *reinterpret_cast<const u16x8*>(vrow + c0);
#pragma unroll
      for (int j = 0; j < 8; ++j) {
        int c = c0 + j;
        vt[c * 256 + (((tid * 2) ^ ((c & 15) << 4)) >> 1)] = vv[j];
      }
    }
    // K: thread tid owns key=tid row.
    const unsigned short* krow = kbase + tid * 32;
#pragma unroll
    for (int c8 = 0; c8 < 4; ++c8)
      *reinterpret_cast<u16x8*>(&Kl[tid * 40 + c8 * 8]) =
          *reinterpret_cast<const u16x8*>(krow + c8 * 8);
  }
  __syncthreads();

  const f32x4 zero = {0.f, 0.f, 0.f, 0.f};
  const int srcA = l15 + (((2 * hi) & 3) << 4);
  const int srcB = l15 + (((2 * hi + 1) & 3) << 4);
  const bool gsel = (hi >= 2);

#pragma unroll 1
  for (int fr = 0; fr < 4; ++fr) {
    const int q0 = w * 64 + fr * 16;
    const float* nbq = nbh + (size_t)(q0 + l15) * 256;

    // ---- prefetch batch 1 (nb kt 0-7), gate, q ----
    f32x4 nbv0[8];
#pragma unroll
    for (int kt = 0; kt < 8; ++kt) {
      float4 t = *reinterpret_cast<const float4*>(nbq + kt * 16 + hi * 4);
      nbv0[kt] = (f32x4){t.x, t.y, t.z, t.w};
    }
    unsigned short gpre[8];
#pragma unroll
    for (int ct = 0; ct < 2; ++ct)
#pragma unroll
      for (int i = 0; i < 4; ++i)
        gpre[ct * 4 + i] = gbase[(q0 + hi * 4 + i) * 32 + ct * 16 + l15];
    u16x8 qf = *reinterpret_cast<const u16x8*>(qbase + (q0 + l15) * 32 + hi * 8);

    // ---- QK^T from LDS K ----
    f32x4 sacc[16];
    __builtin_amdgcn_s_setprio(1);
#pragma unroll
    for (int kt = 0; kt < 16; ++kt) {
      bf16x8 kf = *reinterpret_cast<const bf16x8*>(
          (const char*)Kl + (kt * 16 + l15) * 80 + hi * 16);
      sacc[kt] = __builtin_amdgcn_mfma_f32_16x16x32_bf16(kf, as_bf(qf), zero, 0, 0, 0);
    }
    __builtin_amdgcn_s_setprio(0);

    // ---- bias batch 1, then prefetch batch 2, then bias batch 2 ----
#pragma unroll
    for (int kt = 0; kt < 8; ++kt) {
      float4 mb4 = *reinterpret_cast<const float4*>(&mb[kt * 16 + hi * 4]);
      sacc[kt][0] += mb4.x + nbv0[kt][0];
      sacc[kt][1] += mb4.y + nbv0[kt][1];
      sacc[kt][2] += mb4.z + nbv0[kt][2];
      sacc[kt][3] += mb4.w + nbv0[kt][3];
    }
    f32x4 nbv1[8];
#pragma unroll
    for (int kt = 0; kt < 8; ++kt) {
      float4 t = *reinterpret_cast<const float4*>(nbq + (kt + 8) * 16 + hi * 4);
      nbv1[kt] = (f32x4){t.x, t.y, t.z, t.w};
    }
#pragma unroll
    for (int kt = 0; kt < 8; ++kt) {
      float4 mb4 = *reinterpret_cast<const float4*>(&mb[(kt + 8) * 16 + hi * 4]);
      sacc[kt + 8][0] += mb4.x + nbv1[kt][0];
      sacc[kt + 8][1] += mb4.y + nbv1[kt][1];
      sacc[kt + 8][2] += mb4.z + nbv1[kt][2];
      sacc[kt + 8][3] += mb4.w + nbv1[kt][3];
    }

    // ---- softmax: lane-local 64 + 2 shuffles ----
    float mx = -3.0e38f;
#pragma unroll
    for (int kt = 0; kt < 16; ++kt) {
#pragma unroll
      for (int i = 0; i < 4; ++i) mx = fmaxf(mx, sacc[kt][i]);
    }
    mx = fmaxf(mx, __shfl_xor(mx, 16));
    mx = fmaxf(mx, __shfl_xor(mx, 32));

    float sum = 0.f;
    unsigned int pk0[16], pk1[16];
#pragma unroll
    for (int kt = 0; kt < 16; ++kt) {
      float p0 = __expf(sacc[kt][0] - mx);
      float p1 = __expf(sacc[kt][1] - mx);
      float p2 = __expf(sacc[kt][2] - mx);
      float p3 = __expf(sacc[kt][3] - mx);
      sum += (p0 + p1) + (p2 + p3);
      pk0[kt] = cvtpk(p0, p1);
      pk1[kt] = cvtpk(p2, p3);
    }
    sum += __shfl_xor(sum, 16);
    sum += __shfl_xor(sum, 32);
    const float inv = 1.0f / sum;

    // ---- PV: A-frag assembled by shuffles (2 kt-parity rounds + select) ----
    f32x4 wacc[2];
    wacc[0] = zero; wacc[1] = zero;
    __builtin_amdgcn_s_setprio(1);
#pragma unroll
    for (int ks2 = 0; ks2 < 8; ++ks2) {
      unsigned int a0A = (unsigned int)__shfl((int)pk0[2 * ks2], srcA);
      unsigned int a1A = (unsigned int)__shfl((int)pk1[2 * ks2], srcA);
      unsigned int a2A = (unsigned int)__shfl((int)pk0[2 * ks2], srcB);
      unsigned int a3A = (unsigned int)__shfl((int)pk1[2 * ks2], srcB);
      unsigned int a0B = (unsigned int)__shfl((int)pk0[2 * ks2 + 1], srcA);
      unsigned int a1B = (unsigned int)__shfl((int)pk1[2 * ks2 + 1], srcA);
      unsigned int a2B = (unsigned int)__shfl((int)pk0[2 * ks2 + 1], srcB);
      unsigned int a3B = (unsigned int)__shfl((int)pk1[2 * ks2 + 1], srcB);
      u32x4 afu;
      afu[0] = gsel ? a0B : a0A;
      afu[1] = gsel ? a1B : a1A;
      afu[2] = gsel ? a2B : a2A;
      afu[3] = gsel ? a3B : a3A;
      bf16x8 af = __builtin_bit_cast(bf16x8, afu);
#pragma unroll
      for (int ct = 0; ct < 2; ++ct) {
        bf16x8 vb = *reinterpret_cast<const bf16x8*>(
            (const char*)vt + (ct * 16 + l15) * 512 + ((ks2 * 64 + hi * 16) ^ (l15 << 4)));
        wacc[ct] = __builtin_amdgcn_mfma_f32_16x16x32_bf16(af, vb, wacc[ct], 0, 0, 0);
      }
    }
    __builtin_amdgcn_s_setprio(0);

    // ---- epilogue: inv via shuffle, gated bf16 stores (D: q=hi*4+i, c=ct*16+l15) ----
    float iv[4];
#pragma unroll
    for (int i = 0; i < 4; ++i)
      iv[i] = __shfl(inv, hi * 4 + i);
#pragma unroll
    for (int ct = 0; ct < 2; ++ct) {
#pragma unroll
      for (int i = 0; i < 4; ++i) {
        int q = q0 + hi * 4 + i;
        float o = bf2f(gpre[ct * 4 + i]) * wacc[ct][i] * iv[i];
        wag[((size_t)(b * 256 + q)) * 256 + h * 32 + ct * 16 + l15] = f2bf(o);
      }
    }
  }
}

extern "C" void kernel_launch(void* const* d_in, const int* in_sizes, int n_in,
                              void* d_out, int out_size, void* d_ws, size_t ws_size,
                              hipStream_t stream) {
  const float* x     = (const float*)d_in[0];
  const float* mask  = (const float*)d_in[1];
  const float* nb    = (const float*)d_in[2];
  const float* wqkv  = (const float*)d_in[3];
  const float* wgate = (const float*)d_in[4];
  const float* gbias = (const float*)d_in[5];
  const float* wo    = (const float*)d_in[6];
  const float* bo    = (const float*)d_in[7];
  float* outp = (float*)d_out;

  char* ws = (char*)d_ws;
  unsigned short* xb    = (unsigned short*)(ws);               // 16,777,216 B
  unsigned short* wallb = (unsigned short*)(ws + 16777216);    //    524,288 B
  unsigned short* wob   = (unsigned short*)(ws + 17301504);    //    131,072 B
  unsigned short* qs    = (unsigned short*)(ws + 17432576);    // 16,777,216 B
  unsigned short* ksb   = (unsigned short*)(ws + 34209792);    // 16,777,216 B
  unsigned short* vsb   = (unsigned short*)(ws + 50987008);    // 16,777,216 B
  unsigned short* gateb = (unsigned short*)(ws + 67764224);    // 16,777,216 B
  unsigned short* wag   = xb;  // alias: x_bf dead after K1

  k_convert<<<dim3(8512), dim3(256), 0, stream>>>(x, wqkv, wgate, wo, xb, wallb, wob);
  k_gemm<0><<<dim3(2048), dim3(256), 0, stream>>>(xb, wallb, qs, ksb, vsb, gateb, gbias, nullptr, nullptr);
  k_attn<<<dim3(128, 8), dim3(256), 0, stream>>>(qs, ksb, vsb, gateb, mask, nb, wag);
  k_gemm<1><<<dim3(512), dim3(256), 0, stream>>>(wag, wob, nullptr, nullptr, nullptr, nullptr, nullptr, outp, bo);
}

// Round 9
// 139.281 us; speedup vs baseline: 1.5196x; 1.5196x over previous
//
#include <hip/hip_runtime.h>
#include <stdint.h>

#define B2 128
#define NSEQ 256
#define DIM 256
#define NH 8
#define CH 32

typedef __attribute__((ext_vector_type(8))) __bf16 bf16x8;
typedef __attribute__((ext_vector_type(8))) unsigned short u16x8;
typedef __attribute__((ext_vector_type(4))) unsigned short u16x4;
typedef __attribute__((ext_vector_type(4))) float f32x4;

__device__ __forceinline__ unsigned short f2bf(float f) {
  unsigned int u = __builtin_bit_cast(unsigned int, f);
  u += 0x7FFFu + ((u >> 16) & 1u);
  return (unsigned short)(u >> 16);
}
__device__ __forceinline__ float bf2f(unsigned short h) {
  unsigned int u = ((unsigned int)h) << 16;
  return __builtin_bit_cast(float, u);
}
__device__ __forceinline__ bf16x8 as_bf(u16x8 v) { return __builtin_bit_cast(bf16x8, v); }

__device__ __forceinline__ void gload16(void* lds, const void* g) {
  __builtin_amdgcn_global_load_lds(
      (__attribute__((address_space(1))) void*)(g),
      (__attribute__((address_space(3))) void*)(lds), 16, 0, 0);
}

// ---------------- K0: fp32 -> bf16 conversion ----------------
__global__ void k_convert(const float* __restrict__ x, const float* __restrict__ wqkv,
                          const float* __restrict__ wgate, const float* __restrict__ wo,
                          unsigned short* __restrict__ xb, unsigned short* __restrict__ wallb,
                          unsigned short* __restrict__ wob) {
  const int NX = 8388608, NWALL = 262144, NWO = 65536;
  int i = blockIdx.x * blockDim.x + threadIdx.x;
  int total4 = (NX + NWALL + NWO) >> 2;
  if (i >= total4) return;
  int e = i << 2;
  float4 v;
  unsigned short* dst;
  if (e < NX) {
    v = *reinterpret_cast<const float4*>(x + e);
    dst = xb + e;
  } else if (e < NX + NWALL) {
    int o = e - NX;
    v = (o < 196608) ? *reinterpret_cast<const float4*>(wqkv + o)
                     : *reinterpret_cast<const float4*>(wgate + (o - 196608));
    dst = wallb + o;
  } else {
    int o = e - NX - NWALL;
    v = *reinterpret_cast<const float4*>(wo + o);
    dst = wob + o;
  }
  u16x4 r;
  r[0] = f2bf(v.x); r[1] = f2bf(v.y); r[2] = f2bf(v.z); r[3] = f2bf(v.w);
  *reinterpret_cast<u16x4*>(dst) = r;
}

// ---------------- K1/K3: GEMM  Y = A(bf16) * Bw(bf16)^T ----------------
template <int MODE>
__launch_bounds__(256, 2)
__global__ void k_gemm(const unsigned short* __restrict__ A, const unsigned short* __restrict__ Bw,
                       unsigned short* __restrict__ qs, unsigned short* __restrict__ ksb,
                       unsigned short* __restrict__ vsb, unsigned short* __restrict__ gateb,
                       const float* __restrict__ gbias,
                       float* __restrict__ outp, const float* __restrict__ bo) {
  __shared__ __attribute__((aligned(16))) unsigned short As[2][8192];  // [128][64] bf16, swizzled
  __shared__ __attribute__((aligned(16))) unsigned short Bs[2][8192];
  const int tid = threadIdx.x, lane = tid & 63, w = tid >> 6;
  const int wr = w >> 1, wc = w & 1;
  const int m0 = blockIdx.x * 128, n0 = blockIdx.y * 128;

  auto stage = [&](unsigned short* sbuf, const unsigned short* gsrc, int row0, int k0) {
#pragma unroll
    for (int q2 = 0; q2 < 4; ++q2) {
      int ob = (w * 4 + q2) * 1024 + (lane << 4);
      int r = ob >> 7, cb = ob & 127;
      int scb = cb ^ ((r & 7) << 4);
      const unsigned short* g = gsrc + (size_t)(row0 + r) * 256 + k0 + (scb >> 1);
      gload16(sbuf + (size_t)(w * 4 + q2) * 512, g);
    }
  };

  f32x4 acc[4][4];
#pragma unroll
  for (int i = 0; i < 4; ++i) {
#pragma unroll
    for (int j = 0; j < 4; ++j) acc[i][j] = (f32x4){0.f, 0.f, 0.f, 0.f};
  }

  stage(As[0], A, m0, 0);
  stage(Bs[0], Bw, n0, 0);
  asm volatile("s_waitcnt vmcnt(0)" ::: "memory");
  __syncthreads();

#pragma unroll
  for (int kt = 0; kt < 4; ++kt) {
    const int cur = kt & 1;
    if (kt < 3) {
      stage(As[cur ^ 1], A, m0, (kt + 1) * 64);
      stage(Bs[cur ^ 1], Bw, n0, (kt + 1) * 64);
    }
#pragma unroll
    for (int kk = 0; kk < 2; ++kk) {
      bf16x8 af[4], bfv[4];
      const int cb = kk * 64 + ((lane >> 4) << 4);
#pragma unroll
      for (int fr = 0; fr < 4; ++fr) {
        int ra = wr * 64 + fr * 16 + (lane & 15);
        int off = ra * 128 + (cb ^ ((ra & 7) << 4));
        af[fr] = *reinterpret_cast<const bf16x8*>((const char*)As[cur] + off);
      }
#pragma unroll
      for (int fc = 0; fc < 4; ++fc) {
        int rb = wc * 64 + fc * 16 + (lane & 15);
        int off = rb * 128 + (cb ^ ((rb & 7) << 4));
        bfv[fc] = *reinterpret_cast<const bf16x8*>((const char*)Bs[cur] + off);
      }
#pragma unroll
      for (int fr = 0; fr < 4; ++fr) {
#pragma unroll
        for (int fc = 0; fc < 4; ++fc)
          acc[fr][fc] = __builtin_amdgcn_mfma_f32_16x16x32_bf16(af[fr], bfv[fc], acc[fr][fc], 0, 0, 0);
      }
    }
    asm volatile("s_waitcnt vmcnt(0)" ::: "memory");
    __syncthreads();
  }

  if (MODE == 0) {
#pragma unroll
    for (int fr = 0; fr < 4; ++fr) {
      int mrow = m0 + wr * 64 + fr * 16 + ((lane >> 4) << 2);
      int b = mrow >> 8, n = mrow & 255;
#pragma unroll
      for (int fc = 0; fc < 4; ++fc) {
        int e = n0 + wc * 64 + fc * 16 + (lane & 15);
        int which = e >> 8, loc = e & 255, hh = loc >> 5, cc = loc & 31;
#pragma unroll
        for (int i = 0; i < 4; ++i) {
          float v = acc[fr][fc][i];
          size_t idx = ((size_t)(b * 8 + hh) * 256 + (n + i)) * 32 + cc;
          if (which == 0) {
            qs[idx] = f2bf(v * 0.17677669529663687f);  // C^-0.5
          } else if (which == 1) {
            ksb[idx] = f2bf(v);
          } else if (which == 2) {
            vsb[idx] = f2bf(v);
          } else {
            float gsig = 1.0f / (1.0f + __expf(-(v + gbias[loc])));
            gateb[idx] = f2bf(gsig);  // [bh][n][c] layout, same as q/k/v
          }
        }
      }
    }
  } else {
#pragma unroll
    for (int fr = 0; fr < 4; ++fr) {
      int mrow = m0 + wr * 64 + fr * 16 + ((lane >> 4) << 2);
#pragma unroll
      for (int fc = 0; fc < 4; ++fc) {
        int e = n0 + wc * 64 + fc * 16 + (lane & 15);
        float bb = bo[e];
#pragma unroll
        for (int i = 0; i < 4; ++i)
          outp[(size_t)(mrow + i) * 256 + e] = acc[fr][fc][i] + bb;
      }
    }
  }
}

// ---------------- K2: attention per (b2, head), transposed-S layout ----------------
// Round-2 structure + ONE change: K staged once in LDS (fragment-major Kl),
// per-fr kf fragments re-read from LDS (defeats global-load sinking).
__launch_bounds__(256, 2)
__global__ void k_attn(const unsigned short* __restrict__ qs, const unsigned short* __restrict__ ksb,
                       const unsigned short* __restrict__ vsb, const unsigned short* __restrict__ gateb,
                       const float* __restrict__ mask, const float* __restrict__ nb,
                       unsigned short* __restrict__ wag) {
  __shared__ __attribute__((aligned(16))) unsigned short vt[32][264];        // V^T [c][key]
  __shared__ __attribute__((aligned(16))) unsigned short pch[4][2][16][72];  // per-wave P chunks
  __shared__ __attribute__((aligned(16))) unsigned short Kl[16][16][4][8];   // K frags [kt][l15][hi][8]
  __shared__ __attribute__((aligned(16))) float mb[256];
  __shared__ float invl[4][16];
  const int tid = threadIdx.x, lane = tid & 63, w = tid >> 6;
  const int l15 = lane & 15, hi = lane >> 4;
  const int b = blockIdx.x, h = blockIdx.y;
  const size_t bh = (size_t)(b * 8 + h);
  const unsigned short* kbase = ksb + bh * 8192;
  const unsigned short* vbase = vsb + bh * 8192;
  const unsigned short* qbase = qs + bh * 8192;
  const float* nbh = nb + (size_t)h * 65536;

  mb[tid] = 1e9f * (mask[b * 256 + tid] - 1.0f);
  {
    const unsigned short* vrow = vbase + tid * 32;
#pragma unroll
    for (int c0 = 0; c0 < 32; c0 += 8) {
      u16x8 vv = *reinterpret_cast<const u16x8*>(vrow + c0);
#pragma unroll
      for (int j = 0; j < 8; ++j) vt[c0 + j][tid] = vv[j];
    }
    // K row tid -> fragment-major Kl[tid>>4][tid&15][hi][0..8)
    const unsigned short* krow = kbase + tid * 32;
#pragma unroll
    for (int c8 = 0; c8 < 4; ++c8)
      *reinterpret_cast<u16x8*>(&Kl[tid >> 4][tid & 15][c8][0]) =
          *reinterpret_cast<const u16x8*>(krow + c8 * 8);
  }
  __syncthreads();

  const f32x4 zero = {0.f, 0.f, 0.f, 0.f};
#pragma unroll 1
  for (int fr = 0; fr < 4; ++fr) {
    const int q0 = w * 64 + fr * 16;
    u16x8 qf = *reinterpret_cast<const u16x8*>(qbase + (q0 + l15) * 32 + hi * 8);

    bf16x8 kf16[16];
#pragma unroll
    for (int kt = 0; kt < 16; ++kt)
      kf16[kt] = *reinterpret_cast<const bf16x8*>(&Kl[kt][l15][hi][0]);

    f32x4 sacc[16];
    __builtin_amdgcn_s_setprio(1);
#pragma unroll
    for (int kt = 0; kt < 16; ++kt)
      sacc[kt] = __builtin_amdgcn_mfma_f32_16x16x32_bf16(kf16[kt], as_bf(qf), zero, 0, 0, 0);
    __builtin_amdgcn_s_setprio(0);

    const float* nbq = nbh + (size_t)(q0 + l15) * 256;
#pragma unroll
    for (int kt = 0; kt < 16; ++kt) {
      float4 nb4 = *reinterpret_cast<const float4*>(nbq + kt * 16 + hi * 4);
      float4 mb4 = *reinterpret_cast<const float4*>(&mb[kt * 16 + hi * 4]);
      sacc[kt][0] += mb4.x + nb4.x;
      sacc[kt][1] += mb4.y + nb4.y;
      sacc[kt][2] += mb4.z + nb4.z;
      sacc[kt][3] += mb4.w + nb4.w;
    }
    float mx = -3.0e38f;
#pragma unroll
    for (int kt = 0; kt < 16; ++kt) {
#pragma unroll
      for (int i = 0; i < 4; ++i) mx = fmaxf(mx, sacc[kt][i]);
    }
    mx = fmaxf(mx, __shfl_xor(mx, 16));
    mx = fmaxf(mx, __shfl_xor(mx, 32));

    float sum = 0.f;
    f32x4 wacc[2];
    wacc[0] = zero; wacc[1] = zero;
#pragma unroll
    for (int c = 0; c < 4; ++c) {
      const int buf = c & 1;
#pragma unroll
      for (int ktl = 0; ktl < 4; ++ktl) {
        const int kt = c * 4 + ktl;
        u16x4 pv;
#pragma unroll
        for (int i = 0; i < 4; ++i) {
          float p = __expf(sacc[kt][i] - mx);
          sum += p;
          pv[i] = f2bf(p);  // unnormalized; inv folded into epilogue
        }
        *reinterpret_cast<u16x4*>(&pch[w][buf][l15][ktl * 16 + hi * 4]) = pv;
      }
      asm volatile("s_waitcnt lgkmcnt(0)" ::: "memory");
      __builtin_amdgcn_sched_barrier(0);
      __builtin_amdgcn_s_setprio(1);
#pragma unroll
      for (int ks2 = 0; ks2 < 2; ++ks2) {
        bf16x8 pa = *reinterpret_cast<const bf16x8*>(&pch[w][buf][l15][ks2 * 32 + hi * 8]);
#pragma unroll
        for (int ct = 0; ct < 2; ++ct) {
          bf16x8 vb = *reinterpret_cast<const bf16x8*>(&vt[ct * 16 + l15][c * 64 + ks2 * 32 + hi * 8]);
          wacc[ct] = __builtin_amdgcn_mfma_f32_16x16x32_bf16(pa, vb, wacc[ct], 0, 0, 0);
        }
      }
      __builtin_amdgcn_s_setprio(0);
    }
    sum += __shfl_xor(sum, 16);
    sum += __shfl_xor(sum, 32);
    const float inv = 1.0f / sum;
    if (hi == 0) invl[w][l15] = inv;

    // Epilogue: transpose wacc through LDS (reuse pch[w] buf0 area as [16][36] f32)
    float* et = reinterpret_cast<float*>(&pch[w][0][0][0]);
#pragma unroll
    for (int ct = 0; ct < 2; ++ct) {
#pragma unroll
      for (int i = 0; i < 4; ++i)
        et[(hi * 4 + i) * 36 + ct * 16 + l15] = wacc[ct][i];
    }
    asm volatile("s_waitcnt lgkmcnt(0)" ::: "memory");
    __builtin_amdgcn_sched_barrier(0);
    const int eq = lane >> 2, eh = lane & 3;
    float4 v0 = *reinterpret_cast<const float4*>(&et[eq * 36 + eh * 8]);
    float4 v1 = *reinterpret_cast<const float4*>(&et[eq * 36 + eh * 8 + 4]);
    const float iv = invl[w][eq];
    const int qrow = q0 + eq;
    u16x8 g = *reinterpret_cast<const u16x8*>(gateb + bh * 8192 + qrow * 32 + eh * 8);
    u16x8 ov;
    ov[0] = f2bf(bf2f(g[0]) * v0.x * iv);
    ov[1] = f2bf(bf2f(g[1]) * v0.y * iv);
    ov[2] = f2bf(bf2f(g[2]) * v0.z * iv);
    ov[3] = f2bf(bf2f(g[3]) * v0.w * iv);
    ov[4] = f2bf(bf2f(g[4]) * v1.x * iv);
    ov[5] = f2bf(bf2f(g[5]) * v1.y * iv);
    ov[6] = f2bf(bf2f(g[6]) * v1.z * iv);
    ov[7] = f2bf(bf2f(g[7]) * v1.w * iv);
    *reinterpret_cast<u16x8*>(wag + ((size_t)(b * 256 + qrow)) * 256 + h * 32 + eh * 8) = ov;
    asm volatile("s_waitcnt lgkmcnt(0)" ::: "memory");  // drain et reads before next fr reuses pch
    __builtin_amdgcn_sched_barrier(0);
  }
}

extern "C" void kernel_launch(void* const* d_in, const int* in_sizes, int n_in,
                              void* d_out, int out_size, void* d_ws, size_t ws_size,
                              hipStream_t stream) {
  const float* x     = (const float*)d_in[0];
  const float* mask  = (const float*)d_in[1];
  const float* nb    = (const float*)d_in[2];
  const float* wqkv  = (const float*)d_in[3];
  const float* wgate = (const float*)d_in[4];
  const float* gbias = (const float*)d_in[5];
  const float* wo    = (const float*)d_in[6];
  const float* bo    = (const float*)d_in[7];
  float* outp = (float*)d_out;

  char* ws = (char*)d_ws;
  unsigned short* xb    = (unsigned short*)(ws);               // 16,777,216 B
  unsigned short* wallb = (unsigned short*)(ws + 16777216);    //    524,288 B
  unsigned short* wob   = (unsigned short*)(ws + 17301504);    //    131,072 B
  unsigned short* qs    = (unsigned short*)(ws + 17432576);    // 16,777,216 B
  unsigned short* ksb   = (unsigned short*)(ws + 34209792);    // 16,777,216 B
  unsigned short* vsb   = (unsigned short*)(ws + 50987008);    // 16,777,216 B
  unsigned short* gateb = (unsigned short*)(ws + 67764224);    // 16,777,216 B
  unsigned short* wag   = xb;  // alias: x_bf dead after K1

  k_convert<<<dim3(8512), dim3(256), 0, stream>>>(x, wqkv, wgate, wo, xb, wallb, wob);
  k_gemm<0><<<dim3(256, 8), dim3(256), 0, stream>>>(xb, wallb, qs, ksb, vsb, gateb, gbias, nullptr, nullptr);
  k_attn<<<dim3(128, 8), dim3(256), 0, stream>>>(qs, ksb, vsb, gateb, mask, nb, wag);
  k_gemm<1><<<dim3(256, 2), dim3(256), 0, stream>>>(wag, wob, nullptr, nullptr, nullptr, nullptr, nullptr, outp, bo);
}